// Round 1
// baseline (593.358 us; speedup 1.0000x reference)
//
#include <hip/hip_runtime.h>

#define NB   8
#define NC   64
#define H    128
#define W    128
#define TILE 16
#define HALO 18     // TILE + 2 halo
#define ICH  32     // input channels staged per phase

// Fold the 3x3 kernel into per-parity 2x2 kernels.
// Nearest-2x upsample means, per axis:
//   even out (p=0): taps {-1: w0, 0: w1+w2}
//   odd  out (p=1): taps { 0: w0+w1, +1: w2}
// Layout: w2[((ocg*64 + ic)*8 + ocl)*16 + (pr*2+pc)*4 + i*2 + j]
//   tap (i,j) sits at input offset (pr+i-1, pc+j-1).
__global__ void prep_weights(const float* __restrict__ w, float* __restrict__ w2) {
    int t = blockIdx.x * blockDim.x + threadIdx.x;
    if (t >= NC * NC) return;
    int oc = t >> 6, ic = t & 63;
    const float* wp = w + (oc * NC + ic) * 9;
    float wv[3][3];
#pragma unroll
    for (int kh = 0; kh < 3; ++kh)
#pragma unroll
        for (int kw = 0; kw < 3; ++kw) wv[kh][kw] = wp[kh * 3 + kw];

    // row-combined: rc[pr][i][kw]
    float rc[2][2][3];
#pragma unroll
    for (int kw = 0; kw < 3; ++kw) {
        rc[0][0][kw] = wv[0][kw];
        rc[0][1][kw] = wv[1][kw] + wv[2][kw];
        rc[1][0][kw] = wv[0][kw] + wv[1][kw];
        rc[1][1][kw] = wv[2][kw];
    }
    int ocg = oc >> 3, ocl = oc & 7;
    float* op = w2 + ((ocg * NC + ic) * 8 + ocl) * 16;
#pragma unroll
    for (int pr = 0; pr < 2; ++pr)
#pragma unroll
        for (int pc = 0; pc < 2; ++pc)
#pragma unroll
            for (int i = 0; i < 2; ++i) {
                float c0 = (pc == 0) ? rc[pr][i][0] : (rc[pr][i][0] + rc[pr][i][1]);
                float c1 = (pc == 0) ? (rc[pr][i][1] + rc[pr][i][2]) : rc[pr][i][2];
                op[(pr * 2 + pc) * 4 + i * 2 + 0] = c0;
                op[(pr * 2 + pc) * 4 + i * 2 + 1] = c1;
            }
}

// Block: one 16x16 input tile (-> 32x32 output tile), one batch, one 8-oc group.
// Thread: one input pixel -> 2x2 outputs x 8 oc = 32 accumulators.
__global__ __launch_bounds__(256, 4) void upconv_kernel(
    const float* __restrict__ x, const float* __restrict__ w2,
    const float* __restrict__ bias, float* __restrict__ out) {
    __shared__ float xs[ICH * HALO * HALO];  // 41,472 B

    const int tid = threadIdx.x;
    const int tx = blockIdx.x & 7, ty = blockIdx.x >> 3;
    const int b = blockIdx.y, ocg = blockIdx.z;
    const int r0 = ty * TILE, c0 = tx * TILE;
    const int tr = tid >> 4, tc = tid & 15;

    float acc[8][2][2];
#pragma unroll
    for (int o = 0; o < 8; ++o)
#pragma unroll
        for (int pr = 0; pr < 2; ++pr)
#pragma unroll
            for (int pc = 0; pc < 2; ++pc) acc[o][pr][pc] = 0.f;

    for (int ph = 0; ph < 2; ++ph) {
        // ---- stage 32 channels of the (TILE+2)^2 halo tile, zero-padded ----
        for (int e = tid; e < ICH * HALO * HALO; e += 256) {
            int ic  = e / (HALO * HALO);
            int rem = e - ic * (HALO * HALO);
            int rr  = rem / HALO;
            int cc  = rem - rr * HALO;
            int gr = r0 - 1 + rr, gc = c0 - 1 + cc;
            float v = 0.f;
            if ((unsigned)gr < (unsigned)H && (unsigned)gc < (unsigned)W)
                v = x[((size_t)(b * NC + ph * ICH + ic) * H + gr) * W + gc];
            xs[e] = v;
        }
        __syncthreads();

        const float* wbase = w2 + (size_t)((ocg * NC + ph * ICH) * 8) * 16;
        for (int ic = 0; ic < ICH; ++ic) {
            float xv[3][3];
#pragma unroll
            for (int i = 0; i < 3; ++i)
#pragma unroll
                for (int j = 0; j < 3; ++j)
                    xv[i][j] = xs[ic * (HALO * HALO) + (tr + i) * HALO + (tc + j)];

            const float* wp = wbase + ic * 128;  // 8 oc x 16 combined taps (wave-uniform)
#pragma unroll
            for (int o = 0; o < 8; ++o)
#pragma unroll
                for (int pr = 0; pr < 2; ++pr)
#pragma unroll
                    for (int pc = 0; pc < 2; ++pc)
#pragma unroll
                        for (int i = 0; i < 2; ++i)
#pragma unroll
                            for (int j = 0; j < 2; ++j)
                                acc[o][pr][pc] +=
                                    wp[o * 16 + (pr * 2 + pc) * 4 + i * 2 + j] *
                                    xv[pr + i][pc + j];
        }
        __syncthreads();
    }

    // ---- epilogue: +bias, coalesced float2 stores (both col parities) ----
    const int orow = 2 * (r0 + tr), ocol = 2 * (c0 + tc);
#pragma unroll
    for (int o = 0; o < 8; ++o) {
        const int oc = ocg * 8 + o;
        const float bv = bias[oc];
#pragma unroll
        for (int pr = 0; pr < 2; ++pr) {
            float2 v = make_float2(acc[o][pr][0] + bv, acc[o][pr][1] + bv);
            size_t idx = ((size_t)(b * NC + oc) * 256 + (orow + pr)) * 256 + ocol;
            *reinterpret_cast<float2*>(out + idx) = v;
        }
    }
}

extern "C" void kernel_launch(void* const* d_in, const int* in_sizes, int n_in,
                              void* d_out, int out_size, void* d_ws, size_t ws_size,
                              hipStream_t stream) {
    const float* x    = (const float*)d_in[0];
    const float* wgt  = (const float*)d_in[1];
    const float* bias = (const float*)d_in[2];
    float* out = (float*)d_out;
    float* w2  = (float*)d_ws;  // 64*64*16 floats = 256 KiB

    prep_weights<<<dim3(16), dim3(256), 0, stream>>>(wgt, w2);
    upconv_kernel<<<dim3(64, NB, 8), dim3(256), 0, stream>>>(x, w2, bias, out);
}

// Round 2
// 277.966 us; speedup vs baseline: 2.1346x; 2.1346x over previous
//
#include <hip/hip_runtime.h>

#define NB   8
#define NC   64
#define H    128
#define W    128
#define TILE 16
#define HALO 18          // TILE + 2
#define ICP  72          // padded channel stride (bf16 elems) -> 144 B, breaks b128 bank aliasing

typedef __attribute__((ext_vector_type(8))) short short8;
typedef __attribute__((ext_vector_type(4))) float float4_t;

static __device__ __forceinline__ unsigned short f2bf(float f) {
    unsigned u = __builtin_bit_cast(unsigned, f);
    // round-to-nearest-even
    u += 0x7fffu + ((u >> 16) & 1u);
    return (unsigned short)(u >> 16);
}

// Fold 3x3 into per-parity 2x2 (NN-2x upsample collapse), emit bf16 in exact
// MFMA A-fragment order:
//   k = tap*64 + ic  (tap = i*2+j; tap (i,j) reads input offset (pr+i-1, pc+j-1))
//   frag (p, s, m): p = pr*2+pc, s = k>>5 (MFMA k-step), m = oc>>4 (oc tile)
//   within frag: lane = ((ic>>3)&3)*16 + (oc&15), elem jj = ic&7
//   flat: (((p*8 + s)*4 + m)*64 + lane)*8 + jj     [total 65536 bf16 = 128 KiB]
__global__ void prep_weights(const float* __restrict__ w, unsigned short* __restrict__ Aw) {
    int t = blockIdx.x * blockDim.x + threadIdx.x;
    if (t >= NC * NC) return;
    int oc = t >> 6, ic = t & 63;
    const float* wp = w + (oc * NC + ic) * 9;
    float wv[3][3];
#pragma unroll
    for (int kh = 0; kh < 3; ++kh)
#pragma unroll
        for (int kw = 0; kw < 3; ++kw) wv[kh][kw] = wp[kh * 3 + kw];

    float rc[2][2][3];  // [pr][i][kw]
#pragma unroll
    for (int kw = 0; kw < 3; ++kw) {
        rc[0][0][kw] = wv[0][kw];
        rc[0][1][kw] = wv[1][kw] + wv[2][kw];
        rc[1][0][kw] = wv[0][kw] + wv[1][kw];
        rc[1][1][kw] = wv[2][kw];
    }
    int m = oc >> 4;
    int lane = ((ic >> 3) & 3) * 16 + (oc & 15);
    int jj = ic & 7;
#pragma unroll
    for (int pr = 0; pr < 2; ++pr)
#pragma unroll
        for (int pc = 0; pc < 2; ++pc) {
            int p = pr * 2 + pc;
#pragma unroll
            for (int i = 0; i < 2; ++i)
#pragma unroll
                for (int j = 0; j < 2; ++j) {
                    float v;
                    if (pc == 0) v = (j == 0) ? rc[pr][i][0] : (rc[pr][i][1] + rc[pr][i][2]);
                    else         v = (j == 0) ? (rc[pr][i][0] + rc[pr][i][1]) : rc[pr][i][2];
                    int tap = i * 2 + j;
                    int s = tap * 2 + (ic >> 5);
                    size_t idx = ((((size_t)(p * 8 + s) * 4 + m) * 64 + lane) * 8) + jj;
                    Aw[idx] = f2bf(v);
                }
        }
}

// Block: 16x16 input tile, one batch, one row-parity pr. 256 thr = 4 waves.
// Wave w: pixel rows 4w..4w+3 (4 n-tiles of 16), all 64 oc, both col parities.
// K-loop: 8 MFMA steps over k=(tap,ic-half), no barriers inside.
__global__ __launch_bounds__(256) void upconv_mfma(
    const float* __restrict__ x, const unsigned short* __restrict__ Aw,
    const float* __restrict__ bias, float* __restrict__ out) {
    __shared__ __align__(16) unsigned short xs[HALO * HALO * ICP];  // 46,656 B

    const int tid = threadIdx.x;
    const int tx = blockIdx.x & 7, ty = blockIdx.x >> 3;
    const int b = blockIdx.y, pr = blockIdx.z;
    const int r0 = ty * TILE, c0 = tx * TILE;

    // ---- stage 18x18 halo x 64 ic, fp32 global (px-coalesced) -> bf16 LDS (ch-last) ----
    for (int e = tid; e < HALO * HALO; e += 256) {
        int rr = e / HALO, cc = e - rr * HALO;
        int gr = r0 - 1 + rr, gc = c0 - 1 + cc;
        bool inb = ((unsigned)gr < (unsigned)H) & ((unsigned)gc < (unsigned)W);
        const float* xp = x + (size_t)b * NC * H * W + (size_t)gr * W + gc;
        unsigned* dst = (unsigned*)&xs[e * ICP];
#pragma unroll 8
        for (int ic = 0; ic < NC; ic += 2) {
            float v0 = inb ? xp[(size_t)ic * (H * W)] : 0.f;
            float v1 = inb ? xp[(size_t)(ic + 1) * (H * W)] : 0.f;
            dst[ic >> 1] = (unsigned)f2bf(v0) | ((unsigned)f2bf(v1) << 16);
        }
    }
    __syncthreads();

    const int wave = tid >> 6, lane = tid & 63;
    const int tcl = lane & 15, khi = lane >> 4;

    float4_t acc[4][4][2];  // [oc-tile m][row-tile t][pc]
#pragma unroll
    for (int m = 0; m < 4; ++m)
#pragma unroll
        for (int t = 0; t < 4; ++t)
#pragma unroll
            for (int pc = 0; pc < 2; ++pc) acc[m][t][pc] = (float4_t){0.f, 0.f, 0.f, 0.f};

#pragma unroll
    for (int s = 0; s < 8; ++s) {
        const int i = s >> 2, j = (s >> 1) & 1, ich = (s & 1) * 32;
#pragma unroll
        for (int pc = 0; pc < 2; ++pc) {
            short8 Bf[4];
#pragma unroll
            for (int t = 0; t < 4; ++t) {
                int row = wave * 4 + t + pr + i;
                int col = tcl + pc + j;
                Bf[t] = *(const short8*)&xs[(row * HALO + col) * ICP + ich + khi * 8];
            }
            short8 Af[4];
#pragma unroll
            for (int m = 0; m < 4; ++m)
                Af[m] = *(const short8*)(Aw + (((size_t)((pr * 2 + pc) * 8 + s) * 4 + m) * 64 + lane) * 8);
#pragma unroll
            for (int m = 0; m < 4; ++m)
#pragma unroll
                for (int t = 0; t < 4; ++t)
                    acc[m][t][pc] = __builtin_amdgcn_mfma_f32_16x16x32_bf16(
                        Af[m], Bf[t], acc[m][t][pc], 0, 0, 0);
        }
    }

    // ---- epilogue: +bias, float2 stores (both col parities contiguous) ----
#pragma unroll
    for (int m = 0; m < 4; ++m)
#pragma unroll
        for (int t = 0; t < 4; ++t) {
            const int orow = 2 * (r0 + wave * 4 + t) + pr;
#pragma unroll
            for (int reg = 0; reg < 4; ++reg) {
                const int oc = m * 16 + khi * 4 + reg;
                const float bv = bias[oc];
                float2 v = make_float2(acc[m][t][0][reg] + bv, acc[m][t][1][reg] + bv);
                size_t idx = (((size_t)(b * NC + oc) * 256 + orow) * 256) + 2 * (c0 + tcl);
                *reinterpret_cast<float2*>(out + idx) = v;
            }
        }
}

extern "C" void kernel_launch(void* const* d_in, const int* in_sizes, int n_in,
                              void* d_out, int out_size, void* d_ws, size_t ws_size,
                              hipStream_t stream) {
    const float* x    = (const float*)d_in[0];
    const float* wgt  = (const float*)d_in[1];
    const float* bias = (const float*)d_in[2];
    float* out = (float*)d_out;
    unsigned short* Aw = (unsigned short*)d_ws;  // 65536 bf16 = 128 KiB

    prep_weights<<<dim3(16), dim3(256), 0, stream>>>(wgt, Aw);
    upconv_mfma<<<dim3(64, NB, 2), dim3(256), 0, stream>>>(x, Aw, bias, out);
}